// Round 5
// baseline (343.009 us; speedup 1.0000x reference)
//
#include <hip/hip_runtime.h>

#define THREADS 128
#define BPB 16
#define ITERS 8
#define NBATCH 131072
#define NGRP (NBATCH / BPB)            // 8192
#define NBLOCKS (NGRP / ITERS)         // 1024 = 4 blocks/CU exactly resident

typedef __attribute__((ext_vector_type(8))) _Float16 half8;
typedef __attribute__((ext_vector_type(4))) float f32x4;

// LDS layout (bytes):
//  [0, 20224):      sx   f32 [16][316 dw]   x staging (global_load_lds dest)
//  [20224, 39424):  sxT  f16 [16][15][80B]  xT / y / (out-stage f32 [16][228dw])
//  [39424, 40512):  lbuf f32 [16][17 dw]    logit exchange
#define XB_DW 316
#define Y_RS 80
#define Y_BS 1200
#define XT_OFF 20224
#define LB_OFF 39424
#define SMEM_BYTES 40512
#define OUT_SDW 228

static __device__ __forceinline__ unsigned short f2h(float f) {
    return __builtin_bit_cast(unsigned short, (_Float16)f);   // RNE
}
static __device__ __forceinline__ unsigned int pack2h(float a, float b) {
    return (unsigned int)f2h(a) | ((unsigned int)f2h(b) << 16);
}

// ---- prefetch one batch-group's x into sx via global_load_lds (16B slots) ----
static __device__ __forceinline__ void prefetch_x(const float* __restrict__ x,
                                                  char* smem, int grp, int lane, int wv) {
    const float* xg = x + (size_t)grp * (BPB * 315);
    #pragma unroll
    for (int j = 0; j < 10; ++j) {
        const int chunk = j * 2 + wv;
        const int slot  = chunk * 64 + lane;
        if (slot < 1264) {
            unsigned b  = ((unsigned)slot * 830u) >> 16;          // slot / 79
            unsigned w4 = ((unsigned)slot - b * 79u) * 4u;        // dword offset, mult of 4
            const float* src = xg + b * 315u + w4;
            if (grp == NGRP - 1 && slot == 1263) src -= 1;        // avoid 4B OOB; fixed up in C
            __builtin_amdgcn_global_load_lds(
                (const __attribute__((address_space(1))) unsigned int*)src,
                (__attribute__((address_space(3))) unsigned int*)(smem + chunk * 1024),
                16, 0, 0);
        }
    }
}

// ---- conv0 via MFMA + attention softmax; h kept in regs; y written into sxT ----
template<int P0, int NP>
__device__ __forceinline__ void conv0_att(char* sxT, float* lbuf,
        const half8 (&af0)[2],
        const float* __restrict__ attw, const float* __restrict__ attb,
        int col, int g, int lane) {
    f32x4 h[NP][2];
    #pragma unroll
    for (int i = 0; i < NP; ++i) {
        const int p = P0 + i;
        half8 bf = *(const half8*)(sxT + col * Y_BS + p * Y_RS + g * 16);
        f32x4 z = {0.f, 0.f, 0.f, 0.f};
        h[i][0] = __builtin_amdgcn_mfma_f32_16x16x32_f16(af0[0], bf, z, 0, 0, 0);
        h[i][1] = __builtin_amdgcn_mfma_f32_16x16x32_f16(af0[1], bf, z, 0, 0, 0);
        float4 a0 = *(const float4*)(attw + p * 32 + 4 * g);
        float4 a1 = *(const float4*)(attw + p * 32 + 16 + 4 * g);
        float lp = h[i][0][0] * a0.x + h[i][0][1] * a0.y + h[i][0][2] * a0.z + h[i][0][3] * a0.w
                 + h[i][1][0] * a1.x + h[i][1][1] * a1.y + h[i][1][2] * a1.z + h[i][1][3] * a1.w;
        lp += __shfl_xor(lp, 16, 64);
        lp += __shfl_xor(lp, 32, 64);
        lp += attb[p];
        if (lane < 16) lbuf[lane * 17 + p] = lp;
    }
    __syncthreads();    // logits visible (both waves); all conv0 xT reads done
    float lg[15];
    #pragma unroll
    for (int l = 0; l < 15; ++l) lg[l] = lbuf[col * 17 + l];
    float mx = lg[0];
    #pragma unroll
    for (int l = 1; l < 15; ++l) mx = fmaxf(mx, lg[l]);
    float e[15], sum = 0.f;
    #pragma unroll
    for (int l = 0; l < 15; ++l) { e[l] = __expf(lg[l] - mx); sum += e[l]; }
    const float inv = 1.f / sum;
    #pragma unroll
    for (int i = 0; i < NP; ++i) {
        const int p = P0 + i;
        const float s = e[p] * inv;
        uint2 u0, u1;
        u0.x = pack2h(h[i][0][0] * s, h[i][0][1] * s);
        u0.y = pack2h(h[i][0][2] * s, h[i][0][3] * s);
        u1.x = pack2h(h[i][1][0] * s, h[i][1][1] * s);
        u1.y = pack2h(h[i][1][2] * s, h[i][1][3] * s);
        char* yr = sxT + col * Y_BS + p * Y_RS;
        *(uint2*)(yr + 8 * g) = u0;           // channels 4g..4g+3
        *(uint2*)(yr + 32 + 8 * g) = u1;      // channels 16+4g..19+4g
    }
}

// ---- conv1(+bn1+lrelu) -> reg fragments -> conv2(+bn2+lrelu) -> out-stage in sxT ----
// stage-2 channel permutation: channel(mt,row) = 32*(mt>>1) + 8*(row>>2) + 4*(mt&1) + (row&3)
template<int R0, int NR, int P0, int NP>
__device__ __forceinline__ void stack23(char* sxT, int col, int g,
        const half8 (&af2)[4][3], const float (&sha1v)[16],
        const float* __restrict__ w2, const float (&sha2v)[8], const float (&iva2v)[2]) {
    float* sout = (float*)sxT;
    // row phase: a1 rows R0..R0+NR-1 -> fr register fragments
    half8 fr[NR][2];
    {
        const char* yb = sxT + col * Y_BS;
        half8 y3[3];
        y3[(R0 + 0) % 3] = *(const half8*)(yb + (R0 + 0) * Y_RS + g * 16);
        y3[(R0 + 1) % 3] = *(const half8*)(yb + (R0 + 1) * Y_RS + g * 16);
        #pragma unroll
        for (int i = 0; i < NR; ++i) {
            const int r = R0 + i;
            y3[(r + 2) % 3] = *(const half8*)(yb + (r + 2) * Y_RS + g * 16);
            f32x4 acc0 = {0.f,0.f,0.f,0.f}, acc1 = {0.f,0.f,0.f,0.f};
            f32x4 acc2 = {0.f,0.f,0.f,0.f}, acc3 = {0.f,0.f,0.f,0.f};
            #pragma unroll
            for (int s = 0; s < 3; ++s) {
                const half8 yy = y3[(r + s) % 3];
                acc0 = __builtin_amdgcn_mfma_f32_16x16x32_f16(af2[0][s], yy, acc0, 0,0,0);
                acc1 = __builtin_amdgcn_mfma_f32_16x16x32_f16(af2[1][s], yy, acc1, 0,0,0);
                acc2 = __builtin_amdgcn_mfma_f32_16x16x32_f16(af2[2][s], yy, acc2, 0,0,0);
                acc3 = __builtin_amdgcn_mfma_f32_16x16x32_f16(af2[3][s], yy, acc3, 0,0,0);
            }
            float z[4][4];
            #pragma unroll
            for (int r2 = 0; r2 < 4; ++r2) {
                float t0 = acc0[r2] + sha1v[ 0 + r2]; z[0][r2] = fmaxf(t0, 0.01f * t0);
                float t1 = acc1[r2] + sha1v[ 4 + r2]; z[1][r2] = fmaxf(t1, 0.01f * t1);
                float t2 = acc2[r2] + sha1v[ 8 + r2]; z[2][r2] = fmaxf(t2, 0.01f * t2);
                float t3 = acc3[r2] + sha1v[12 + r2]; z[3][r2] = fmaxf(t3, 0.01f * t3);
            }
            uint4 u0, u1;
            u0.x = pack2h(z[0][0], z[0][1]); u0.y = pack2h(z[0][2], z[0][3]);
            u0.z = pack2h(z[1][0], z[1][1]); u0.w = pack2h(z[1][2], z[1][3]);
            u1.x = pack2h(z[2][0], z[2][1]); u1.y = pack2h(z[2][2], z[2][3]);
            u1.z = pack2h(z[3][0], z[3][1]); u1.w = pack2h(z[3][2], z[3][3]);
            fr[i][0] = __builtin_bit_cast(half8, u0);
            fr[i][1] = __builtin_bit_cast(half8, u1);
        }
    }
    __syncthreads();   // all y reads done before out-stage overwrites sxT region

    // p phase: conv2 from register fragments (af3 rebuilt per iteration)
    half8 af3[2][6];
    #pragma unroll
    for (int mt = 0; mt < 2; ++mt) {
        const int o = mt * 16 + col;
        if (o < 20) {
            const float iva = iva2v[mt];
            #pragma unroll
            for (int hh = 0; hh < 2; ++hh) {
                const float* wp = w2 + o * 192 + hh * 96 + g * 24;
                float f[24];
                #pragma unroll
                for (int q = 0; q < 6; ++q) {
                    float4 v = *(const float4*)(wp + 4 * q);
                    f[4*q+0]=v.x; f[4*q+1]=v.y; f[4*q+2]=v.z; f[4*q+3]=v.w;
                }
                #pragma unroll
                for (int tap = 0; tap < 3; ++tap) {
                    half8 fh;
                    #pragma unroll
                    for (int j = 0; j < 8; ++j) fh[j] = (_Float16)(f[j*3+tap] * iva);
                    af3[mt][tap*2 + hh] = fh;
                }
            }
        } else {
            #pragma unroll
            for (int s = 0; s < 6; ++s) {
                half8 zf;
                #pragma unroll
                for (int j = 0; j < 8; ++j) zf[j] = (_Float16)0.f;
                af3[mt][s] = zf;
            }
        }
    }
    #pragma unroll
    for (int pp = 0; pp < NP; ++pp) {
        const int p = P0 + pp;
        f32x4 acc0 = {0.f,0.f,0.f,0.f}, acc1 = {0.f,0.f,0.f,0.f};
        #pragma unroll
        for (int s = 0; s < 6; ++s) {
            const half8 bf = fr[pp + (s >> 1)][s & 1];
            acc0 = __builtin_amdgcn_mfma_f32_16x16x32_f16(af3[0][s], bf, acc0, 0,0,0);
            acc1 = __builtin_amdgcn_mfma_f32_16x16x32_f16(af3[1][s], bf, acc1, 0,0,0);
        }
        #pragma unroll
        for (int r = 0; r < 4; ++r) {
            const int o0 = 4 * g + r;
            float t0 = acc0[r] + sha2v[r];
            t0 = fmaxf(t0, 0.01f * t0);
            sout[col * OUT_SDW + o0 * 11 + p] = t0;
            const int o1 = 16 + 4 * g + r;
            if (o1 < 20) {
                float t1 = acc1[r] + sha2v[4 + r];
                t1 = fmaxf(t1, 0.01f * t1);
                sout[col * OUT_SDW + o1 * 11 + p] = t1;
            }
        }
    }
}

__global__ __launch_bounds__(THREADS, 2)
void peptide_persist(const float* __restrict__ x,
                     const float* __restrict__ w0,
                     const float* __restrict__ attw,
                     const float* __restrict__ attb,
                     const float* __restrict__ w1,
                     const float* __restrict__ cb1,
                     const float* __restrict__ g1, const float* __restrict__ bt1,
                     const float* __restrict__ mn1, const float* __restrict__ vr1,
                     const float* __restrict__ w2,
                     const float* __restrict__ cb2,
                     const float* __restrict__ g2, const float* __restrict__ bt2,
                     const float* __restrict__ mn2, const float* __restrict__ vr2,
                     float* __restrict__ out) {
    __shared__ __align__(16) char smem[SMEM_BYTES];
    float* sx   = (float*)smem;
    char*  sxT  = smem + XT_OFF;
    float* lbuf = (float*)(smem + LB_OFF);

    const int tid  = threadIdx.x;
    const int lane = tid & 63;
    const int wv   = tid >> 6;
    const int col  = lane & 15;
    const int g    = lane >> 4;
    const int g0   = blockIdx.x * ITERS;

    // ---- prefetch group 0, then build persistent weight fragments (overlaps latency) ----
    prefetch_x(x, smem, g0, lane, wv);

    half8 af0[2];
    #pragma unroll
    for (int mt = 0; mt < 2; ++mt) {
        const int o = mt * 16 + col;
        #pragma unroll
        for (int j = 0; j < 8; ++j) {
            const int c = 8 * g + j;
            af0[mt][j] = (c < 21) ? (_Float16)w0[o * 21 + c] : (_Float16)0.f;
        }
    }
    half8 af2[4][3];
    #pragma unroll
    for (int mt = 0; mt < 4; ++mt) {
        const int o = 32 * (mt >> 1) + 8 * (col >> 2) + 4 * (mt & 1) + (col & 3);
        const float iva = g1[o] * rsqrtf(vr1[o] + 1e-5f);
        const float* wp = w1 + o * 96 + g * 24;
        float f[24];
        #pragma unroll
        for (int q = 0; q < 6; ++q) {
            float4 v = *(const float4*)(wp + 4 * q);
            f[4*q+0]=v.x; f[4*q+1]=v.y; f[4*q+2]=v.z; f[4*q+3]=v.w;
        }
        #pragma unroll
        for (int s = 0; s < 3; ++s) {
            half8 fh;
            #pragma unroll
            for (int j = 0; j < 8; ++j) fh[j] = (_Float16)(f[j*3+s] * iva);
            af2[mt][s] = fh;
        }
    }
    float sha1v[16];
    #pragma unroll
    for (int mt = 0; mt < 4; ++mt)
    #pragma unroll
    for (int r = 0; r < 4; ++r) {
        const int o = 32 * (mt >> 1) + 8 * g + 4 * (mt & 1) + r;
        const float iva = g1[o] * rsqrtf(vr1[o] + 1e-5f);
        sha1v[mt*4+r] = bt1[o] + (cb1[o] - mn1[o]) * iva;
    }
    float iva2v[2];
    #pragma unroll
    for (int mt = 0; mt < 2; ++mt) {
        const int o = mt * 16 + col;
        iva2v[mt] = (o < 20) ? g2[o] * rsqrtf(vr2[o] + 1e-5f) : 0.f;
    }
    float sha2v[8];
    #pragma unroll
    for (int mt = 0; mt < 2; ++mt)
    #pragma unroll
    for (int r = 0; r < 4; ++r) {
        const int o = mt * 16 + 4 * g + r;
        if (o < 20) {
            const float iva = g2[o] * rsqrtf(vr2[o] + 1e-5f);
            sha2v[mt*4+r] = bt2[o] + (cb2[o] - mn2[o]) * iva;
        } else sha2v[mt*4+r] = 0.f;
    }

    #pragma unroll 1
    for (int it = 0; it < ITERS; ++it) {
        const int grp = g0 + it;

        asm volatile("s_waitcnt vmcnt(0)" ::: "memory");
        __syncthreads();                       // prefetched x landed; prev copy-out done

        if (grp == NGRP - 1 && tid < 3) {      // repair the clamped final 16B slot
            sx[15 * XB_DW + 312 + tid] = x[(size_t)41287677 + tid];
        }
        __syncthreads();

        // ---- transpose/convert: sx f32 [b][c][15] -> sxT f16 [b][p][c32, pad 0] ----
        for (int u = tid; u < 240; u += THREADS) {
            const int b = (u * 4370) >> 16;    // u / 15
            const int p = u - b * 15;
            const float* xc = sx + b * XB_DW + p;
            float v[21];
            #pragma unroll
            for (int c = 0; c < 21; ++c) v[c] = xc[c * 15];
            char* dst = sxT + b * Y_BS + p * Y_RS;
            uint4 u0, u1, u2, u3;
            u0.x = pack2h(v[0], v[1]);   u0.y = pack2h(v[2], v[3]);
            u0.z = pack2h(v[4], v[5]);   u0.w = pack2h(v[6], v[7]);
            u1.x = pack2h(v[8], v[9]);   u1.y = pack2h(v[10], v[11]);
            u1.z = pack2h(v[12], v[13]); u1.w = pack2h(v[14], v[15]);
            u2.x = pack2h(v[16], v[17]); u2.y = pack2h(v[18], v[19]);
            u2.z = pack2h(v[20], 0.f);   u2.w = 0u;
            u3.x = 0u; u3.y = 0u; u3.z = 0u; u3.w = 0u;
            *(uint4*)(dst)      = u0;
            *(uint4*)(dst + 16) = u1;
            *(uint4*)(dst + 32) = u2;
            *(uint4*)(dst + 48) = u3;
        }
        __syncthreads();                       // xT ready; sx dead

        if (it + 1 < ITERS) prefetch_x(x, smem, grp + 1, lane, wv);   // fills sx during compute

        // ---- conv0 MFMA + attention (y in-place into sxT) ----
        if (wv == 0) conv0_att<0, 8>(sxT, lbuf, af0, attw, attb, col, g, lane);
        else         conv0_att<8, 7>(sxT, lbuf, af0, attw, attb, col, g, lane);
        __syncthreads();                       // y complete

        // ---- conv1 -> regs -> conv2 -> out-stage (into sxT region) ----
        if (wv == 0) stack23<0, 8, 0, 6>(sxT, col, g, af2, sha1v, w2, sha2v, iva2v);
        else         stack23<6, 7, 6, 5>(sxT, col, g, af2, sha1v, w2, sha2v, iva2v);
        __syncthreads();                       // out-stage complete

        // ---- coalesced nontemporal copy-out ----
        const size_t obase = (size_t)grp * BPB * 220;
        #pragma unroll
        for (int j = 0; j < 8; ++j) {
            const int u = tid + j * THREADS;
            if (u < 912) {
                unsigned b = ((unsigned)u * 1150u) >> 16;   // u / 57
                unsigned r = (unsigned)u - b * 57u;
                if (r < 55u) {
                    f32x4 v = *(const f32x4*)(sxT + u * 16);
                    __builtin_nontemporal_store(v, (f32x4*)(out + obase + b * 220 + r * 4));
                }
            }
        }
        // loop-top barrier orders these reads/stores vs next iteration's writes
    }
}

extern "C" void kernel_launch(void* const* d_in, const int* in_sizes, int n_in,
                              void* d_out, int out_size, void* d_ws, size_t ws_size,
                              hipStream_t stream) {
    const float* x    = (const float*)d_in[0];
    const float* w0   = (const float*)d_in[1];
    const float* attw = (const float*)d_in[2];
    const float* attb = (const float*)d_in[3];
    const float* w1   = (const float*)d_in[4];
    const float* cb1  = (const float*)d_in[5];
    const float* g1   = (const float*)d_in[6];
    const float* bt1  = (const float*)d_in[7];
    const float* mn1  = (const float*)d_in[8];
    const float* vr1  = (const float*)d_in[9];
    const float* w2   = (const float*)d_in[10];
    const float* cb2  = (const float*)d_in[11];
    const float* g2   = (const float*)d_in[12];
    const float* bt2  = (const float*)d_in[13];
    const float* mn2  = (const float*)d_in[14];
    const float* vr2  = (const float*)d_in[15];

    dim3 grid(NBLOCKS);
    dim3 block(THREADS);
    hipLaunchKernelGGL(peptide_persist, grid, block, 0, stream,
                       x, w0, attw, attb,
                       w1, cb1, g1, bt1, mn1, vr1,
                       w2, cb2, g2, bt2, mn2, vr2,
                       (float*)d_out);
}